// Round 1
// baseline (917.585 us; speedup 1.0000x reference)
//
#include <hip/hip_runtime.h>

#define NB 2
#define NN 512
#define NC 256
#define OUTP 14
#define SS 28
#define POOL_PER_BOX (NC * OUTP * OUTP)          // 50176
#define POOL_TOTAL (NB * NN * POOL_PER_BOX)      // 51380224
#define BOX_OFF POOL_TOTAL
#define KEEP_OFF (POOL_TOTAL + NB * NN * 4)

// ---------------- K1: stable sort by score (desc), emit sorted meta ----------------
__global__ __launch_bounds__(512) void k_sort(const float* __restrict__ boxes,
                                              const float* __restrict__ scores,
                                              float4* __restrict__ ws_box,
                                              float2* __restrict__ ws_al,
                                              int* __restrict__ ws_ord) {
    int b = blockIdx.x;
    int tid = threadIdx.x;
    __shared__ float sS[NN];
    __shared__ int sI[NN];
    sS[tid] = scores[b * NN + tid];
    sI[tid] = tid;
    __syncthreads();
    // bitonic sort, "ascending" under comparator: (s desc, idx asc) == stable argsort(-s)
    for (int k = 2; k <= NN; k <<= 1) {
        for (int j = k >> 1; j > 0; j >>= 1) {
            int ixj = tid ^ j;
            if (ixj > tid) {
                float s1 = sS[tid], s2 = sS[ixj];
                int i1 = sI[tid], i2 = sI[ixj];
                bool lt = (s1 > s2) || (s1 == s2 && i1 < i2);  // tid-elem precedes ixj-elem
                bool up = ((tid & k) == 0);
                if (up ? !lt : lt) {
                    sS[tid] = s2; sS[ixj] = s1;
                    sI[tid] = i2; sI[ixj] = i1;
                }
            }
            __syncthreads();
        }
    }
    int o = sI[tid];
    float4 bx = ((const float4*)boxes)[b * NN + o];  // cx, cy, w, h
    float w = bx.z, h = bx.w;
    float x1 = bx.x - w * 0.5f, y1 = bx.y - h * 0.5f;
    float x2 = bx.x + w * 0.5f, y2 = bx.y + h * 0.5f;
    float s = sqrtf(w * h);
    // level = clip(floor(3 + log2(s/224)), 1, 4) via exact pow2 boundaries
    int lvl = (s < 112.f) ? 1 : ((s < 224.f) ? 2 : ((s < 448.f) ? 3 : 4));
    ws_box[b * NN + tid] = make_float4(x1, y1, x2, y2);
    ws_al[b * NN + tid] = make_float2((x2 - x1) * (y2 - y1), (float)lvl);
    ws_ord[b * NN + tid] = o;
}

// ---------------- K2: suppression bitmask matrix ----------------
// grid = NB * 64 blocks (8 rowgroups x 8 colgroups), 64 threads.
// block computes sup[i][cg] word for i = rg*64 + lane (bit k <=> j = cg*64 + k).
__global__ __launch_bounds__(64) void k_sup(const float4* __restrict__ ws_box,
                                            const float2* __restrict__ ws_al,
                                            unsigned long long* __restrict__ ws_sup) {
    int flat = blockIdx.x;
    int batch = flat >> 6;
    int t = flat & 63;
    int rg = t >> 3, cg = t & 7;
    int lane = threadIdx.x;
    int i = rg * 64 + lane;
    float4 bi = ws_box[batch * NN + i];
    float2 ai = ws_al[batch * NN + i];
    float areai = ai.x;
    int il = (int)ai.y;
    unsigned long long m = 0ull;
    int jb = cg * 64;
#pragma unroll 4
    for (int k = 0; k < 64; ++k) {
        int j = jb + k;
        float4 bj = ws_box[batch * NN + j];   // wave-uniform -> broadcast
        float2 aj = ws_al[batch * NN + j];
        float xx1 = fmaxf(bi.x, bj.x);
        float yy1 = fmaxf(bi.y, bj.y);
        float xx2 = fminf(bi.z, bj.z);
        float yy2 = fminf(bi.w, bj.w);
        float iw = fmaxf(xx2 - xx1, 0.0f);
        float ih = fmaxf(yy2 - yy1, 0.0f);
        float inter = iw * ih;
        float denom = areai + aj.x - inter + 1e-9f;
        bool sup = (j > i) && ((int)aj.y == il) && ((inter / denom) > 0.5f);
        m |= sup ? (1ull << k) : 0ull;
    }
    ws_sup[(size_t)(batch * NN + i) * 8 + cg] = m;
}

// ---------------- K3: sequential greedy + write keep/out_boxes ----------------
__global__ __launch_bounds__(64) void k_greedy(const unsigned long long* __restrict__ ws_sup,
                                               const int* __restrict__ ws_ord,
                                               const float* __restrict__ boxes,
                                               float* __restrict__ dout) {
    int b = blockIdx.x;
    int lane = threadIdx.x;
    int myw = lane & 7;  // lanes replicate words 0..7
    const unsigned long long* sup = ws_sup + (size_t)b * NN * 8;
    unsigned long long kwl = ~0ull;  // lane's keep word (word myw)
    for (int w = 0; w < 8; ++w) {
        unsigned long long aw = __shfl(kwl, w);  // active word w (uniform)
        int ibase = w << 6;
        for (int bb = 0; bb < 64; ++bb) {
            int i = ibase + bb;
            unsigned long long rw = sup[(size_t)i * 8 + w];    // uniform
            unsigned long long rl = sup[(size_t)i * 8 + myw];  // per-lane
            if ((aw >> bb) & 1ull) {   // uniform branch
                aw &= ~rw;
                kwl &= ~rl;
            }
        }
    }
    __shared__ unsigned long long skw[8];
    __shared__ char korig[NN];
    if (lane < 8) skw[lane] = kwl;
    __syncthreads();
    for (int i = lane; i < NN; i += 64) {
        int bit = (int)((skw[i >> 6] >> (i & 63)) & 1ull);
        korig[ws_ord[b * NN + i]] = (char)bit;
    }
    __syncthreads();
    for (int n = lane; n < NN; n += 64) {
        float4 bx = ((const float4*)boxes)[b * NN + n];
        float kf = korig[n] ? 1.0f : 0.0f;
        float x1 = (bx.x - bx.z * 0.5f) * kf;
        float y1 = (bx.y - bx.w * 0.5f) * kf;
        float x2 = (bx.x + bx.z * 0.5f) * kf;
        float y2 = (bx.y + bx.w * 0.5f) * kf;
        ((float4*)(dout + BOX_OFF))[b * NN + n] = make_float4(x1, y1, x2, y2);
        dout[KEEP_OFF + b * NN + n] = kf;
    }
}

// ---------------- K4: ROI align (one block per box) ----------------
__global__ __launch_bounds__(256) void k_roi(const float* __restrict__ p4,
                                             const float* __restrict__ p8,
                                             const float* __restrict__ p16,
                                             const float* __restrict__ p32,
                                             const float* __restrict__ boxes,
                                             float* __restrict__ dout) {
    int blk = blockIdx.x;          // 0..1023
    int b = blk >> 9;
    float* obase = dout + (size_t)blk * POOL_PER_BOX;
    float keepf = dout[KEEP_OFF + blk];
    if (keepf < 0.5f) {
        float4 z = make_float4(0.f, 0.f, 0.f, 0.f);
        float4* o4 = (float4*)obase;
        for (int i = threadIdx.x; i < POOL_PER_BOX / 4; i += 256) o4[i] = z;
        return;
    }
    float4 bx = ((const float4*)boxes)[blk];
    float w = bx.z, h = bx.w;
    float s = sqrtf(w * h);
    int lvl = (s < 112.f) ? 0 : ((s < 224.f) ? 1 : ((s < 448.f) ? 2 : 3));
    const float* feat = (lvl == 0) ? p4 : ((lvl == 1) ? p8 : ((lvl == 2) ? p16 : p32));
    int HW = 256 >> lvl;
    float inv = 1.0f / (float)(4 << lvl);
    int planesz = HW * HW;
    const float* plane0 = feat + (size_t)b * NC * planesz;

    __shared__ int sX0[SS], sX1[SS], sY0[SS], sY1[SS];
    __shared__ float sLX[SS], sLY[SS];
    if (threadIdx.x < SS) {
        int t = threadIdx.x;
        float g = (t + 0.5f) * 0.5f;           // (i+0.5)/RATIO
        float x1r = (bx.x - w * 0.5f) * inv;
        float x2r = (bx.x + w * 0.5f) * inv;
        float bwr = (x2r - x1r) / 14.0f;
        float xs = fminf(fmaxf(x1r + g * bwr, 0.0f), (float)(HW - 1));
        float x0f = floorf(xs);
        int x0 = (int)x0f;
        sX0[t] = x0;
        sX1[t] = min(x0 + 1, HW - 1);
        sLX[t] = xs - x0f;
        float y1r = (bx.y - h * 0.5f) * inv;
        float y2r = (bx.y + h * 0.5f) * inv;
        float bhr = (y2r - y1r) / 14.0f;
        float ys = fminf(fmaxf(y1r + g * bhr, 0.0f), (float)(HW - 1));
        float y0f = floorf(ys);
        int y0 = (int)y0f;
        sY0[t] = y0 * HW;
        sY1[t] = min(y0 + 1, HW - 1) * HW;
        sLY[t] = ys - y0f;
    }
    __syncthreads();

    for (unsigned idx = threadIdx.x; idx < POOL_PER_BOX; idx += 256) {
        unsigned c = idx / 196u;
        unsigned p = idx - c * 196u;
        unsigned py = p / 14u;
        unsigned px = p - py * 14u;
        const float* pl = plane0 + (size_t)c * planesz;
        int ix = 2 * px, iy = 2 * py;
        float acc = 0.0f;
#pragma unroll
        for (int dy = 0; dy < 2; ++dy) {
            int yr0 = sY0[iy + dy], yr1 = sY1[iy + dy];
            float ly = sLY[iy + dy];
#pragma unroll
            for (int dx = 0; dx < 2; ++dx) {
                int x0 = sX0[ix + dx], x1 = sX1[ix + dx];
                float lx = sLX[ix + dx];
                float f00 = pl[yr0 + x0], f01 = pl[yr0 + x1];
                float f10 = pl[yr1 + x0], f11 = pl[yr1 + x1];
                float top = f00 + lx * (f01 - f00);
                float bot = f10 + lx * (f11 - f10);
                acc += top + ly * (bot - top);
            }
        }
        obase[idx] = acc * 0.25f;
    }
}

extern "C" void kernel_launch(void* const* d_in, const int* in_sizes, int n_in,
                              void* d_out, int out_size, void* d_ws, size_t ws_size,
                              hipStream_t stream) {
    const float* p4 = (const float*)d_in[0];
    const float* p8 = (const float*)d_in[1];
    const float* p16 = (const float*)d_in[2];
    const float* p32 = (const float*)d_in[3];
    const float* boxes = (const float*)d_in[4];
    const float* scores = (const float*)d_in[5];
    float* out = (float*)d_out;

    char* ws = (char*)d_ws;
    float4* ws_box = (float4*)ws;                              // 2*512*16 = 16384 B
    float2* ws_al = (float2*)(ws + 16384);                     // 2*512*8  =  8192 B
    int* ws_ord = (int*)(ws + 24576);                          // 2*512*4  =  4096 B
    unsigned long long* ws_sup = (unsigned long long*)(ws + 28672);  // 2*512*64 = 65536 B

    k_sort<<<NB, NN, 0, stream>>>(boxes, scores, ws_box, ws_al, ws_ord);
    k_sup<<<NB * 64, 64, 0, stream>>>(ws_box, ws_al, ws_sup);
    k_greedy<<<NB, 64, 0, stream>>>(ws_sup, ws_ord, boxes, out);
    k_roi<<<NB * NN, 256, 0, stream>>>(p4, p8, p16, p32, boxes, out);
}

// Round 2
// 762.150 us; speedup vs baseline: 1.2039x; 1.2039x over previous
//
#include <hip/hip_runtime.h>

#define NB 2
#define NN 512
#define NC 256
#define OUTP 14
#define SS 28
#define CH_SPLIT 4
#define CH_PER_BLK (NC / CH_SPLIT)                     // 64
#define ELEMS_PER_BLK (CH_PER_BLK * OUTP * OUTP)       // 12544 = 256*49
#define POOL_PER_BOX (NC * OUTP * OUTP)                // 50176
#define POOL_TOTAL (NB * NN * POOL_PER_BOX)
#define BOX_OFF POOL_TOTAL
#define KEEP_OFF (POOL_TOTAL + NB * NN * 4)

// ---------------- K1: fused NMS (sort + suppression matrix + greedy), one block per batch ----
__global__ __launch_bounds__(512) void k_nms(const float* __restrict__ boxes,
                                             const float* __restrict__ scores,
                                             float* __restrict__ dout) {
    int b = blockIdx.x;
    int tid = threadIdx.x;
    __shared__ float sS[NN];
    __shared__ int sI[NN];
    __shared__ float4 sB[NN];
    __shared__ float sA[NN];
    __shared__ int sL[NN];
    __shared__ unsigned long long sup[NN][8];   // 32 KB
    __shared__ unsigned long long skw[8];
    __shared__ int korig[NN];

    sS[tid] = scores[b * NN + tid];
    sI[tid] = tid;
    __syncthreads();
    // bitonic sort: (score desc, idx asc) == stable argsort(-scores)
    for (int k = 2; k <= NN; k <<= 1) {
        for (int j = k >> 1; j > 0; j >>= 1) {
            int ixj = tid ^ j;
            if (ixj > tid) {
                float s1 = sS[tid], s2 = sS[ixj];
                int i1 = sI[tid], i2 = sI[ixj];
                bool lt = (s1 > s2) || (s1 == s2 && i1 < i2);
                bool up = ((tid & k) == 0);
                if (up ? !lt : lt) {
                    sS[tid] = s2; sS[ixj] = s1;
                    sI[tid] = i2; sI[ixj] = i1;
                }
            }
            __syncthreads();
        }
    }
    // sorted-order meta
    {
        int o = sI[tid];
        float4 bx = ((const float4*)boxes)[b * NN + o];  // cx,cy,w,h
        float w = bx.z, h = bx.w;
        float x1 = bx.x - w * 0.5f, y1 = bx.y - h * 0.5f;
        float x2 = bx.x + w * 0.5f, y2 = bx.y + h * 0.5f;
        float s = sqrtf(w * h);
        int lvl = (s < 112.f) ? 1 : ((s < 224.f) ? 2 : ((s < 448.f) ? 3 : 4));
        sB[tid] = make_float4(x1, y1, x2, y2);
        sA[tid] = (x2 - x1) * (y2 - y1);
        sL[tid] = lvl;
    }
    __syncthreads();
    // suppression matrix: row tid, 8 x u64 column words
    {
        float4 bi = sB[tid];
        float areai = sA[tid];
        int il = sL[tid];
        for (int cg = 0; cg < 8; ++cg) {
            unsigned long long m = 0ull;
            int jb = cg << 6;
#pragma unroll 4
            for (int k = 0; k < 64; ++k) {
                int j = jb + k;
                float4 bj = sB[j];
                float xx1 = fmaxf(bi.x, bj.x);
                float yy1 = fmaxf(bi.y, bj.y);
                float xx2 = fminf(bi.z, bj.z);
                float yy2 = fminf(bi.w, bj.w);
                float inter = fmaxf(xx2 - xx1, 0.0f) * fmaxf(yy2 - yy1, 0.0f);
                float denom = areai + sA[j] - inter + 1e-9f;
                bool sp = (j > tid) && (sL[j] == il) && ((inter / denom) > 0.5f);
                m |= sp ? (1ull << k) : 0ull;
            }
            sup[tid][cg] = m;
        }
    }
    __syncthreads();
    // greedy: wave 0 only, replicated-state (lane l owns keep-word l&7)
    if (tid < 64) {
        int myw = tid & 7;
        unsigned long long kwl = ~0ull;
        for (int w = 0; w < 8; ++w) {
            unsigned long long aw = __shfl(kwl, w);  // active word w (uniform)
            int ibase = w << 6;
            for (int bb = 0; bb < 64; ++bb) {
                int i = ibase + bb;
                unsigned long long rw = sup[i][w];
                unsigned long long rl = sup[i][myw];
                if ((aw >> bb) & 1ull) {
                    aw &= ~rw;
                    kwl &= ~rl;
                }
            }
        }
        if (tid < 8) skw[tid] = kwl;
    }
    __syncthreads();
    korig[sI[tid]] = (int)((skw[tid >> 6] >> (tid & 63)) & 1ull);
    __syncthreads();
    {
        float4 bx = ((const float4*)boxes)[b * NN + tid];
        float kf = korig[tid] ? 1.0f : 0.0f;
        float x1 = (bx.x - bx.z * 0.5f) * kf;
        float y1 = (bx.y - bx.w * 0.5f) * kf;
        float x2 = (bx.x + bx.z * 0.5f) * kf;
        float y2 = (bx.y + bx.w * 0.5f) * kf;
        ((float4*)(dout + BOX_OFF))[b * NN + tid] = make_float4(x1, y1, x2, y2);
        dout[KEEP_OFF + b * NN + tid] = kf;
    }
}

// ---------------- K2: ROI align, 4 blocks per box (64 channels each) ----------------
__global__ __launch_bounds__(256) void k_roi(const float* __restrict__ p4,
                                             const float* __restrict__ p8,
                                             const float* __restrict__ p16,
                                             const float* __restrict__ p32,
                                             const float* __restrict__ boxes,
                                             float* __restrict__ dout) {
    int blk = blockIdx.x;              // box*CH_SPLIT + chunk
    int box = blk >> 2;
    int chunk = blk & 3;
    int b = box >> 9;
    float* obase = dout + (size_t)box * POOL_PER_BOX + (size_t)chunk * ELEMS_PER_BLK;
    float keepf = dout[KEEP_OFF + box];
    if (keepf < 0.5f) {
        float4 z = make_float4(0.f, 0.f, 0.f, 0.f);
        float4* o4 = (float4*)obase;
        for (int i = threadIdx.x; i < ELEMS_PER_BLK / 4; i += 256) o4[i] = z;
        return;
    }
    float4 bx = ((const float4*)boxes)[box];
    float w = bx.z, h = bx.w;
    float s = sqrtf(w * h);
    int lvl = (s < 112.f) ? 0 : ((s < 224.f) ? 1 : ((s < 448.f) ? 2 : 3));
    const float* feat = (lvl == 0) ? p4 : ((lvl == 1) ? p8 : ((lvl == 2) ? p16 : p32));
    int HW = 256 >> lvl;
    float inv = 1.0f / (float)(4 << lvl);
    int planesz = HW * HW;
    const float* plane0 = feat + (size_t)b * NC * planesz + (size_t)(chunk * CH_PER_BLK) * planesz;

    __shared__ int sX0[SS], sX1[SS], sY0[SS], sY1[SS];
    __shared__ float sLX[SS], sLY[SS];
    if (threadIdx.x < SS) {
        int t = threadIdx.x;
        float g = (t + 0.5f) * 0.5f;
        float x1r = (bx.x - w * 0.5f) * inv;
        float x2r = (bx.x + w * 0.5f) * inv;
        float bwr = (x2r - x1r) / 14.0f;
        float xs = fminf(fmaxf(x1r + g * bwr, 0.0f), (float)(HW - 1));
        float x0f = floorf(xs);
        int x0 = (int)x0f;
        sX0[t] = x0;
        sX1[t] = min(x0 + 1, HW - 1);
        sLX[t] = xs - x0f;
        float y1r = (bx.y - h * 0.5f) * inv;
        float y2r = (bx.y + h * 0.5f) * inv;
        float bhr = (y2r - y1r) / 14.0f;
        float ys = fminf(fmaxf(y1r + g * bhr, 0.0f), (float)(HW - 1));
        float y0f = floorf(ys);
        int y0 = (int)y0f;
        sY0[t] = y0 * HW;
        sY1[t] = min(y0 + 1, HW - 1) * HW;
        sLY[t] = ys - y0f;
    }
    __syncthreads();

    int tid = threadIdx.x;
#pragma unroll 2
    for (int k = 0; k < ELEMS_PER_BLK / 256; ++k) {   // 49 exact iterations
        unsigned idx = tid + (unsigned)k * 256u;
        unsigned c = idx / 196u;
        unsigned p = idx - c * 196u;
        unsigned py = p / 14u;
        unsigned px = p - py * 14u;
        const float* pl = plane0 + (size_t)c * planesz;
        int ix = 2 * px, iy = 2 * py;
        float acc = 0.0f;
#pragma unroll
        for (int dy = 0; dy < 2; ++dy) {
            int yr0 = sY0[iy + dy], yr1 = sY1[iy + dy];
            float ly = sLY[iy + dy];
#pragma unroll
            for (int dx = 0; dx < 2; ++dx) {
                int x0 = sX0[ix + dx], x1 = sX1[ix + dx];
                float lx = sLX[ix + dx];
                float f00 = pl[yr0 + x0], f01 = pl[yr0 + x1];
                float f10 = pl[yr1 + x0], f11 = pl[yr1 + x1];
                float top = f00 + lx * (f01 - f00);
                float bot = f10 + lx * (f11 - f10);
                acc += top + ly * (bot - top);
            }
        }
        obase[idx] = acc * 0.25f;
    }
}

extern "C" void kernel_launch(void* const* d_in, const int* in_sizes, int n_in,
                              void* d_out, int out_size, void* d_ws, size_t ws_size,
                              hipStream_t stream) {
    const float* p4 = (const float*)d_in[0];
    const float* p8 = (const float*)d_in[1];
    const float* p16 = (const float*)d_in[2];
    const float* p32 = (const float*)d_in[3];
    const float* boxes = (const float*)d_in[4];
    const float* scores = (const float*)d_in[5];
    float* out = (float*)d_out;

    k_nms<<<NB, NN, 0, stream>>>(boxes, scores, out);
    k_roi<<<NB * NN * CH_SPLIT, 256, 0, stream>>>(p4, p8, p16, p32, boxes, out);
}